// Round 4
// baseline (201.299 us; speedup 1.0000x reference)
//
#include <hip/hip_runtime.h>
#include <hip/hip_bf16.h>

typedef unsigned short ushortT;
typedef unsigned int uintT;
typedef __attribute__((ext_vector_type(8))) short short8;
typedef __attribute__((ext_vector_type(4))) float f32x4;

#define BATCH   2048
#define NELEC   64
#define BN_EPS  1e-5f

// ws layout (float offsets)
#define OFF_AMEAN  4096                 // 64
#define OFF_SS1    4160                 // scale1[64], shift1[64]
#define OFF_SS2    4288                 // scale2[128], shift2[128]
#define OFF_PS1    4544                 // [64 slots][64] sums
#define OFF_PQ1    8640                 // [64][64] sumsq
#define OFF_PS2    12736                // [64][128]
#define OFF_PQ2    20928                // [64][128]  (ends 29120)
#define OFF_ABF    29120                // ushort: A_hi[4096], A_lo[4096]
#define OFF_W1T    33216                // ushort: W1t_hi[4096], W1t_lo[4096]  (W1t[o][k])
#define OFF_W2T    37312                // ushort: W2t_hi[8192], W2t_lo[8192]  (W2t[o][k])
#define OFF_H1     45504                // ushort h1 strip-major [2048][4][64][16]
#define OFF_H2     4239808              // ushort h2 strip-major [2048][8][64][16]

#define MFMA(a, b, c) __builtin_amdgcn_mfma_f32_16x16x32_bf16(a, b, c, 0, 0, 0)

__device__ inline float bf2f(ushortT u) { return __uint_as_float(((uintT)u) << 16); }
__device__ inline ushortT f2bf(float f) {
  uintT u = __float_as_uint(f);
  u = (u + 0x7FFFu + ((u >> 16) & 1u)) >> 16;
  return (ushortT)u;
}
__device__ inline void split2(float f, ushortT& hi, ushortT& lo) {
  hi = f2bf(f);
  lo = f2bf(f - bf2f(hi));
}
__device__ inline void split8(const float* f, short8& hi, short8& lo) {
  #pragma unroll
  for (int e = 0; e < 8; ++e) {
    ushortT h, l;
    split2(f[e], h, l);
    hi[e] = (short)h; lo[e] = (short)l;
  }
}

// ---------------- prep: build A (bf16 hi/lo), amean, W1t/W2t hi/lo ----------------
__global__ __launch_bounds__(256) void prep_kernel(const int* __restrict__ src,
    const int* __restrict__ dst, int E,
    const float* __restrict__ W1, const float* __restrict__ W2,
    float* __restrict__ ws) {
  __shared__ float degS[NELEC];
  __shared__ float As[NELEC * NELEC];
  int t = threadIdx.x;
  if (t < NELEC) degS[t] = 1.0f;               // self-loop
  for (int i = t; i < NELEC * NELEC; i += 256) As[i] = 0.0f;
  __syncthreads();
  for (int e = t; e < E; e += 256) atomicAdd(&degS[dst[e]], 1.0f);
  __syncthreads();
  for (int e = t; e < E; e += 256) {
    float en = rsqrtf(degS[src[e]]) * rsqrtf(degS[dst[e]]);
    atomicAdd(&As[dst[e] * NELEC + src[e]], en);
  }
  __syncthreads();
  if (t < NELEC) As[t * NELEC + t] += 1.0f / degS[t];
  __syncthreads();
  ushortT* abf = (ushortT*)(ws + OFF_ABF);
  for (int i = t; i < 4096; i += 256) {
    ushortT hi, lo; split2(As[i], hi, lo);
    abf[i] = hi; abf[4096 + i] = lo;
  }
  if (t < NELEC) {
    float s = 0.0f;
    for (int n = 0; n < NELEC; ++n) s += As[n * NELEC + t];
    ws[OFF_AMEAN + t] = s * (1.0f / NELEC);
  }
  ushortT* w1t = (ushortT*)(ws + OFF_W1T);
  for (int i = t; i < 4096; i += 256) {
    int o = i >> 6, k = i & 63;
    ushortT hi, lo; split2(W1[k * 64 + o], hi, lo);
    w1t[i] = hi; w1t[4096 + i] = lo;
  }
  ushortT* w2t = (ushortT*)(ws + OFF_W2T);
  for (int i = t; i < 8192; i += 256) {
    int o = i >> 6, k = i & 63;
    ushortT hi, lo; split2(W2[k * 128 + o], hi, lo);
    w2t[i] = hi; w2t[8192 + i] = lo;
  }
}

// ---------------- layer 1: h1 = A*(x@W1)+b1 (block-per-item, 4 waves) ----------------
__global__ __launch_bounds__(256, 4) void layer1_mfma(const float* __restrict__ x,
    const float* __restrict__ b1, float* __restrict__ ws) {
  __shared__ ushortT FH[4096];          // X frag-order [kg][m][8], hi
  __shared__ ushortT FL[4096];          // lo
  __shared__ ushortT Ts[4][2][1152];    // per-wave T bounce [hi/lo][c*72 + m]
  const int item = blockIdx.x, t = threadIdx.x;
  // cooperative X build: thread -> row m = t>>2, k-range (t&3)*16
  {
    const int m = t >> 2, q = t & 3;
    const float* xp = x + (size_t)item * 4096 + m * 64 + q * 16;
    float f[16];
    *(float4*)&f[0]  = *(const float4*)(xp);
    *(float4*)&f[4]  = *(const float4*)(xp + 4);
    *(float4*)&f[8]  = *(const float4*)(xp + 8);
    *(float4*)&f[12] = *(const float4*)(xp + 12);
    short8 h0, l0, h1v, l1v;
    split8(f, h0, l0);
    split8(f + 8, h1v, l1v);
    const int base = q * 1024 + m * 8;   // kg = q*2 (+1)
    *(short8*)&FH[base] = h0; *(short8*)&FH[base + 512] = h1v;
    *(short8*)&FL[base] = l0; *(short8*)&FL[base + 512] = l1v;
  }
  __syncthreads();
  const int w = t >> 6, lane = t & 63, c = lane & 15, g = lane >> 4;
  // X fragments from LDS
  short8 Xhi[4][2], Xlo[4][2];
  #pragma unroll
  for (int rt = 0; rt < 4; ++rt) {
    #pragma unroll
    for (int ks = 0; ks < 2; ++ks) {
      const int a = (ks * 4 + g) * 512 + (rt * 16 + c) * 8;
      Xhi[rt][ks] = *(const short8*)&FH[a];
      Xlo[rt][ks] = *(const short8*)&FL[a];
    }
  }
  const ushortT* abf = (const ushortT*)(ws + OFF_ABF);
  const ushortT* w1t = (const ushortT*)(ws + OFF_W1T);
  ushortT* tsh = &Ts[w][0][0];
  ushortT* tsl = &Ts[w][1][0];
  const int s = w;   // one strip per wave
  // GEMM1 strip: T[:, s*16..] = X @ W1[:, strip]
  f32x4 tacc[4] = {{0,0,0,0},{0,0,0,0},{0,0,0,0},{0,0,0,0}};
  #pragma unroll
  for (int ks = 0; ks < 2; ++ks) {
    short8 bh = *(const short8*)(w1t + (s * 16 + c) * 64 + ks * 32 + g * 8);
    short8 bl = *(const short8*)(w1t + 4096 + (s * 16 + c) * 64 + ks * 32 + g * 8);
    #pragma unroll
    for (int rt = 0; rt < 4; ++rt) {
      tacc[rt] = MFMA(Xhi[rt][ks], bh, tacc[rt]);
      tacc[rt] = MFMA(Xhi[rt][ks], bl, tacc[rt]);
      tacc[rt] = MFMA(Xlo[rt][ks], bh, tacc[rt]);
    }
  }
  // bounce strip to LDS transposed: Ts[c][m], hi/lo
  #pragma unroll
  for (int rt = 0; rt < 4; ++rt) {
    ushortT h0, h1_, h2_, h3, l0, l1, l2, l3;
    split2(tacc[rt][0], h0, l0); split2(tacc[rt][1], h1_, l1);
    split2(tacc[rt][2], h2_, l2); split2(tacc[rt][3], h3, l3);
    uint2 wh, wl;
    wh.x = (uintT)h0 | ((uintT)h1_ << 16); wh.y = (uintT)h2_ | ((uintT)h3 << 16);
    wl.x = (uintT)l0 | ((uintT)l1 << 16);  wl.y = (uintT)l2 | ((uintT)l3 << 16);
    const int idx = c * 72 + rt * 16 + g * 4;
    *(uint2*)(tsh + idx) = wh;
    *(uint2*)(tsl + idx) = wl;
  }
  // GEMM2 strip: h[:, strip] = A @ T-strip
  f32x4 hacc[4] = {{0,0,0,0},{0,0,0,0},{0,0,0,0},{0,0,0,0}};
  #pragma unroll
  for (int ks = 0; ks < 2; ++ks) {
    short8 th = *(const short8*)(tsh + c * 72 + ks * 32 + g * 8);
    short8 tl = *(const short8*)(tsl + c * 72 + ks * 32 + g * 8);
    #pragma unroll
    for (int rt = 0; rt < 4; ++rt) {
      short8 ah = *(const short8*)(abf + (rt * 16 + c) * 64 + ks * 32 + g * 8);
      short8 al = *(const short8*)(abf + 4096 + (rt * 16 + c) * 64 + ks * 32 + g * 8);
      hacc[rt] = MFMA(ah, th, hacc[rt]);
      hacc[rt] = MFMA(ah, tl, hacc[rt]);
      hacc[rt] = MFMA(al, th, hacc[rt]);
    }
  }
  // epilogue: +bias, stats, strip-major dense store
  const float bias = b1[s * 16 + c];
  ushortT* h1p = (ushortT*)(ws + OFF_H1) + (size_t)item * 4096 + s * 1024;
  float S = 0.0f, Q = 0.0f;
  #pragma unroll
  for (int rt = 0; rt < 4; ++rt) {
    #pragma unroll
    for (int r = 0; r < 4; ++r) {
      float v = hacc[rt][r] + bias;
      S += v; Q += v * v;
      h1p[(rt * 16 + g * 4 + r) * 16 + c] = f2bf(v);
    }
  }
  S += __shfl_xor(S, 16); S += __shfl_xor(S, 32);
  Q += __shfl_xor(Q, 16); Q += __shfl_xor(Q, 32);
  if (g == 0) {
    const int slot = item & 63;
    atomicAdd(&ws[OFF_PS1 + slot * 64 + s * 16 + c], S);
    atomicAdd(&ws[OFF_PQ1 + slot * 64 + s * 16 + c], Q);
  }
}

// ---------------- BN finalize ----------------
__global__ void reduce1_kernel(const float* __restrict__ g1, const float* __restrict__ be1,
                               float* __restrict__ ws) {
  int t = threadIdx.x;
  if (t < 64) {
    float S = 0.0f, Q = 0.0f;
    for (int s = 0; s < 64; ++s) { S += ws[OFF_PS1 + s * 64 + t]; Q += ws[OFF_PQ1 + s * 64 + t]; }
    const float inv = 1.0f / (float)(BATCH * NELEC);
    float m = S * inv;
    float v = fmaxf(Q * inv - m * m, 0.0f);
    float sc = g1[t] * rsqrtf(v + BN_EPS);
    ws[OFF_SS1 + t] = sc;
    ws[OFF_SS1 + 64 + t] = fmaf(-m, sc, be1[t]);
  }
}

__global__ void reduce2_kernel(const float* __restrict__ g2, const float* __restrict__ be2,
                               float* __restrict__ ws) {
  int t = threadIdx.x;
  if (t < 128) {
    float S = 0.0f, Q = 0.0f;
    for (int s = 0; s < 64; ++s) { S += ws[OFF_PS2 + s * 128 + t]; Q += ws[OFF_PQ2 + s * 128 + t]; }
    const float inv = 1.0f / (float)(BATCH * NELEC);
    float m = S * inv;
    float v = fmaxf(Q * inv - m * m, 0.0f);
    float sc = g2[t] * rsqrtf(v + BN_EPS);
    ws[OFF_SS2 + t] = sc;
    ws[OFF_SS2 + 128 + t] = fmaf(-m, sc, be2[t]);
  }
}

// ---------------- layer 2: h2 = A*(relu(bn(h1))@W2)+b2 (block-per-item, 4 waves) ----------------
__global__ __launch_bounds__(256, 4) void layer2_mfma(const float* __restrict__ b2,
    float* __restrict__ ws) {
  __shared__ ushortT FH[4096];          // Y frag-order [kg][m][8], hi
  __shared__ ushortT FL[4096];
  __shared__ ushortT Ts[4][2][1152];
  const int item = blockIdx.x, t = threadIdx.x;
  // cooperative Y = relu(bn(h1)) build
  {
    const int m = t >> 2, q = t & 3, k0 = q * 16;
    const ushortT* hp = (const ushortT*)(ws + OFF_H1) + (size_t)item * 4096 + q * 1024 + m * 16;
    short8 ha = *(const short8*)hp;
    short8 hb = *(const short8*)(hp + 8);
    const float* s1 = ws + OFF_SS1 + k0;
    const float* t1 = ws + OFF_SS1 + 64 + k0;
    float f[16];
    #pragma unroll
    for (int e = 0; e < 8; ++e)
      f[e] = fmaxf(fmaf(bf2f((ushortT)ha[e]), s1[e], t1[e]), 0.0f);
    #pragma unroll
    for (int e = 0; e < 8; ++e)
      f[8 + e] = fmaxf(fmaf(bf2f((ushortT)hb[e]), s1[8 + e], t1[8 + e]), 0.0f);
    short8 h0, l0, h1v, l1v;
    split8(f, h0, l0);
    split8(f + 8, h1v, l1v);
    const int base = q * 1024 + m * 8;
    *(short8*)&FH[base] = h0; *(short8*)&FH[base + 512] = h1v;
    *(short8*)&FL[base] = l0; *(short8*)&FL[base + 512] = l1v;
  }
  __syncthreads();
  const int w = t >> 6, lane = t & 63, c = lane & 15, g = lane >> 4;
  short8 Yhi[4][2], Ylo[4][2];
  #pragma unroll
  for (int rt = 0; rt < 4; ++rt) {
    #pragma unroll
    for (int ks = 0; ks < 2; ++ks) {
      const int a = (ks * 4 + g) * 512 + (rt * 16 + c) * 8;
      Yhi[rt][ks] = *(const short8*)&FH[a];
      Ylo[rt][ks] = *(const short8*)&FL[a];
    }
  }
  const ushortT* abf = (const ushortT*)(ws + OFF_ABF);
  const ushortT* w2t = (const ushortT*)(ws + OFF_W2T);
  ushortT* tsh = &Ts[w][0][0];
  ushortT* tsl = &Ts[w][1][0];
  ushortT* h2p0 = (ushortT*)(ws + OFF_H2) + (size_t)item * 8192;

  #pragma unroll
  for (int si = 0; si < 2; ++si) {
    const int s = w * 2 + si;
    // GEMM1 strip
    f32x4 tacc[4] = {{0,0,0,0},{0,0,0,0},{0,0,0,0},{0,0,0,0}};
    #pragma unroll
    for (int ks = 0; ks < 2; ++ks) {
      short8 bh = *(const short8*)(w2t + (s * 16 + c) * 64 + ks * 32 + g * 8);
      short8 bl = *(const short8*)(w2t + 8192 + (s * 16 + c) * 64 + ks * 32 + g * 8);
      #pragma unroll
      for (int rt = 0; rt < 4; ++rt) {
        tacc[rt] = MFMA(Yhi[rt][ks], bh, tacc[rt]);
        tacc[rt] = MFMA(Yhi[rt][ks], bl, tacc[rt]);
        tacc[rt] = MFMA(Ylo[rt][ks], bh, tacc[rt]);
      }
    }
    #pragma unroll
    for (int rt = 0; rt < 4; ++rt) {
      ushortT h0, h1_, h2_, h3, l0, l1, l2, l3;
      split2(tacc[rt][0], h0, l0); split2(tacc[rt][1], h1_, l1);
      split2(tacc[rt][2], h2_, l2); split2(tacc[rt][3], h3, l3);
      uint2 wh, wl;
      wh.x = (uintT)h0 | ((uintT)h1_ << 16); wh.y = (uintT)h2_ | ((uintT)h3 << 16);
      wl.x = (uintT)l0 | ((uintT)l1 << 16);  wl.y = (uintT)l2 | ((uintT)l3 << 16);
      const int idx = c * 72 + rt * 16 + g * 4;
      *(uint2*)(tsh + idx) = wh;
      *(uint2*)(tsl + idx) = wl;
    }
    // GEMM2 strip
    f32x4 hacc[4] = {{0,0,0,0},{0,0,0,0},{0,0,0,0},{0,0,0,0}};
    #pragma unroll
    for (int ks = 0; ks < 2; ++ks) {
      short8 th = *(const short8*)(tsh + c * 72 + ks * 32 + g * 8);
      short8 tl = *(const short8*)(tsl + c * 72 + ks * 32 + g * 8);
      #pragma unroll
      for (int rt = 0; rt < 4; ++rt) {
        short8 ah = *(const short8*)(abf + (rt * 16 + c) * 64 + ks * 32 + g * 8);
        short8 al = *(const short8*)(abf + 4096 + (rt * 16 + c) * 64 + ks * 32 + g * 8);
        hacc[rt] = MFMA(ah, th, hacc[rt]);
        hacc[rt] = MFMA(ah, tl, hacc[rt]);
        hacc[rt] = MFMA(al, th, hacc[rt]);
      }
    }
    const float bias = b2[s * 16 + c];
    ushortT* h2p = h2p0 + s * 1024;
    float S = 0.0f, Q = 0.0f;
    #pragma unroll
    for (int rt = 0; rt < 4; ++rt) {
      #pragma unroll
      for (int r = 0; r < 4; ++r) {
        float v = hacc[rt][r] + bias;
        S += v; Q += v * v;
        h2p[(rt * 16 + g * 4 + r) * 16 + c] = f2bf(v);
      }
    }
    S += __shfl_xor(S, 16); S += __shfl_xor(S, 32);
    Q += __shfl_xor(Q, 16); Q += __shfl_xor(Q, 32);
    if (g == 0) {
      const int slot = item & 63;
      atomicAdd(&ws[OFF_PS2 + slot * 128 + s * 16 + c], S);
      atomicAdd(&ws[OFF_PQ2 + slot * 128 + s * 16 + c], Q);
    }
  }
}

// ---------------- layer 3 (+ mean pool): out[b] = (amean@relu(bn2(h2[b])))@W3 + b3 ----------------
__global__ __launch_bounds__(64) void layer3_kernel(const float* __restrict__ W3,
    const float* __restrict__ b3, const float* __restrict__ ws,
    float* __restrict__ out) {
  const int item = blockIdx.x, lane = threadIdx.x;
  const int f0 = lane * 2;
  const float s2a = ws[OFF_SS2 + f0],       s2b = ws[OFF_SS2 + f0 + 1];
  const float t2a = ws[OFF_SS2 + 128 + f0], t2b = ws[OFF_SS2 + 128 + f0 + 1];
  const float* am = ws + OFF_AMEAN;
  const ushortT* h2 = (const ushortT*)(ws + OFF_H2) + (size_t)item * 8192
                      + (f0 >> 4) * 1024 + (f0 & 15);
  float v0 = 0.0f, v1 = 0.0f;
  #pragma unroll 8
  for (int m = 0; m < 64; ++m) {
    uintT pk = *(const uintT*)(h2 + m * 16);
    float y0 = fmaxf(fmaf(bf2f((ushortT)(pk & 0xffffu)), s2a, t2a), 0.0f);
    float y1 = fmaxf(fmaf(bf2f((ushortT)(pk >> 16)),     s2b, t2b), 0.0f);
    float a = am[m];
    v0 = fmaf(a, y0, v0);
    v1 = fmaf(a, y1, v1);
  }
  float o0 = b3[f0], o1 = b3[f0 + 1];
  #pragma unroll 8
  for (int k = 0; k < 128; ++k) {
    float vk = __shfl((k & 1) ? v1 : v0, k >> 1, 64);
    o0 = fmaf(vk, W3[k * 128 + f0],     o0);
    o1 = fmaf(vk, W3[k * 128 + f0 + 1], o1);
  }
  float2 ov; ov.x = o0; ov.y = o1;
  *(float2*)(out + (size_t)item * 128 + f0) = ov;
}

extern "C" void kernel_launch(void* const* d_in, const int* in_sizes, int n_in,
                              void* d_out, int out_size, void* d_ws, size_t ws_size,
                              hipStream_t stream) {
  const float* x   = (const float*)d_in[0];
  const float* W1  = (const float*)d_in[1];
  const float* b1  = (const float*)d_in[2];
  const float* W2  = (const float*)d_in[3];
  const float* b2  = (const float*)d_in[4];
  const float* W3  = (const float*)d_in[5];
  const float* b3  = (const float*)d_in[6];
  const float* g1  = (const float*)d_in[7];
  const float* be1 = (const float*)d_in[8];
  const float* g2  = (const float*)d_in[9];
  const float* be2 = (const float*)d_in[10];
  const int*   src = (const int*)d_in[11];
  const int*   dst = (const int*)d_in[12];
  const int E = in_sizes[11];
  float* ws  = (float*)d_ws;
  float* out = (float*)d_out;

  // zero BN partial-stat slots (PS1..PQ2)
  hipMemsetAsync((void*)(ws + OFF_PS1), 0, (size_t)(29120 - OFF_PS1) * 4, stream);
  hipLaunchKernelGGL(prep_kernel,   dim3(1),     dim3(256), 0, stream, src, dst, E, W1, W2, ws);
  hipLaunchKernelGGL(layer1_mfma,   dim3(BATCH), dim3(256), 0, stream, x, b1, ws);
  hipLaunchKernelGGL(reduce1_kernel,dim3(1),     dim3(64),  0, stream, g1, be1, ws);
  hipLaunchKernelGGL(layer2_mfma,   dim3(BATCH), dim3(256), 0, stream, b2, ws);
  hipLaunchKernelGGL(reduce2_kernel,dim3(1),     dim3(128), 0, stream, g2, be2, ws);
  hipLaunchKernelGGL(layer3_kernel, dim3(BATCH), dim3(64),  0, stream, W3, b3, ws, out);
}